// Round 1
// baseline (392.042 us; speedup 1.0000x reference)
//
#include <hip/hip_runtime.h>
#include <hip/hip_bf16.h>
#include <math.h>
#include <float.h>

// dims
constexpr int NQ = 64, NK = 256, SSZ = 64, D = 512, FF = 2048;
constexpr int PAIRS = NQ * NK;          // 16384
constexpr int ROWSX = 2 * PAIRS;        // 32768
constexpr int NX = (NQ + NK) * SSZ;     // 20480 rows of X = [tgt;mem]

typedef __bf16 bf16x8 __attribute__((ext_vector_type(8)));
typedef float floatx16 __attribute__((ext_vector_type(16)));

// async global->LDS, 16 B per lane; LDS dest = wave-uniform base + lane*16
__device__ __forceinline__ void gl2lds16(const unsigned short* g, unsigned short* l) {
    __builtin_amdgcn_global_load_lds(
        (const __attribute__((address_space(1))) unsigned int*)(g),
        (__attribute__((address_space(3))) unsigned int*)(l),
        16, 0, 0);
}

// ---------------- K0: sigmoid of score_embed (or 1.0 if !flag) -------------
__global__ void k_sig(const float* __restrict__ se, const int* __restrict__ flag,
                      float* __restrict__ sig) {
    int i = blockIdx.x * blockDim.x + threadIdx.x;
    if (i < SSZ * SSZ) {
        sig[i] = (*flag) ? 1.0f / (1.0f + expf(-se[i])) : 1.0f;
    }
}

// ---------------- K0b: convert X=[tgt;mem], W1, W2 to bf16 -----------------
__global__ __launch_bounds__(256) void k_cvt(
        const float* __restrict__ tgt, const float* __restrict__ mem,
        const float* __restrict__ W1, const float* __restrict__ W2,
        __hip_bfloat16* __restrict__ Xb, __hip_bfloat16* __restrict__ W1b,
        __hip_bfloat16* __restrict__ W2b) {
    constexpr int T4 = NQ * SSZ * D / 4;   // tgt float4 count
    constexpr int X4 = NX * D / 4;         // X float4 count
    constexpr int W4 = D * D / 4;          // W1 float4 count
    constexpr int V4 = FF * 64 / 4;        // W2 float4 count
    int idx = blockIdx.x * 256 + threadIdx.x;
    if (idx >= X4 + W4 + V4) return;
    const float* src;
    __hip_bfloat16* dst;
    if (idx < T4)           { src = tgt + (size_t)idx * 4;             dst = Xb + (size_t)idx * 4; }
    else if (idx < X4)      { src = mem + (size_t)(idx - T4) * 4;      dst = Xb + (size_t)idx * 4; }
    else if (idx < X4 + W4) { src = W1 + (size_t)(idx - X4) * 4;       dst = W1b + (size_t)(idx - X4) * 4; }
    else                    { src = W2 + (size_t)(idx - X4 - W4) * 4;  dst = W2b + (size_t)(idx - X4 - W4) * 4; }
    float4 v = *reinterpret_cast<const float4*>(src);
    union { __hip_bfloat16 h[4]; uint2 u; } o;
    o.h[0] = __float2bfloat16(v.x); o.h[1] = __float2bfloat16(v.y);
    o.h[2] = __float2bfloat16(v.z); o.h[3] = __float2bfloat16(v.w);
    *reinterpret_cast<uint2*>(dst) = o.u;
}

// ---------------- K1: MFMA GEMM1: C = Xb @ W1b^T + b1 (bf16 out) -----------
// 128x128 tile; async global->LDS staging with XOR-swizzled source chunks.
// LDS layout: tile row = 64 bf16 (128 B = 8 chunks); slot (r, p) holds
// global chunk p ^ (r&7); read offset = ((st*2+h) ^ (c&7))*8 elems.
__global__ __launch_bounds__(256, 3) void k_gemm1_mfma(
        const __hip_bfloat16* __restrict__ Xb, const __hip_bfloat16* __restrict__ W1b,
        const float* __restrict__ b1, const int* __restrict__ flag,
        __hip_bfloat16* __restrict__ C) {
    __shared__ __attribute__((aligned(16))) unsigned short lds[2 * 128 * 64]; // 32 KB
    const unsigned short* Xu = reinterpret_cast<const unsigned short*>(Xb);
    const unsigned short* Wu = reinterpret_cast<const unsigned short*>(W1b);
    unsigned short* Cu = reinterpret_cast<unsigned short*>(C);

    int tid = threadIdx.x;
    int bm = blockIdx.x >> 2, bn = blockIdx.x & 3;
    int m0 = bm * 128, n0 = bn * 128;

    if (!(*flag)) {
#pragma unroll
        for (int i = 0; i < 8; ++i) {
            int id = i * 256 + tid;
            int row = id >> 4, ch = id & 15;
            uint4 v = *reinterpret_cast<const uint4*>(Xu + (size_t)(m0 + row) * D + n0 + ch * 8);
            *reinterpret_cast<uint4*>(Cu + (size_t)(m0 + row) * D + n0 + ch * 8) = v;
        }
        return;
    }

    int w = tid >> 6, l = tid & 63, h = l >> 5, c = l & 31;
    int wm = w >> 1, wn = w & 1;
    int chg = (l & 7) ^ (l >> 3);     // swizzled source chunk for this lane
    int cx = c & 7;
    floatx16 acc00 = {}, acc01 = {}, acc10 = {}, acc11 = {};

    for (int kb = 0; kb < D; kb += 64) {
#pragma unroll
        for (int j = 0; j < 8; ++j) {
            int i = w * 8 + j;              // 0..31
            int buf = i >> 4;               // 0: A(X), 1: B(W1)
            int rb = (i & 15) * 8;
            int r = rb + (l >> 3);
            const unsigned short* src = (buf == 0)
                ? (Xu + (size_t)(m0 + r) * D + kb + chg * 8)
                : (Wu + (size_t)(n0 + r) * D + kb + chg * 8);
            gl2lds16(src, lds + buf * 8192 + rb * 64);
        }
        __syncthreads();
        const unsigned short* pA = lds + (wm * 64) * 64;
        const unsigned short* pB = lds + 8192 + (wn * 64) * 64;
#pragma unroll
        for (int st = 0; st < 4; ++st) {
            int ko = ((st * 2 + h) ^ cx) * 8;
            bf16x8 a0 = *reinterpret_cast<const bf16x8*>(pA + c * 64 + ko);
            bf16x8 a1 = *reinterpret_cast<const bf16x8*>(pA + (32 + c) * 64 + ko);
            bf16x8 b0 = *reinterpret_cast<const bf16x8*>(pB + c * 64 + ko);
            bf16x8 b1 = *reinterpret_cast<const bf16x8*>(pB + (32 + c) * 64 + ko);
            acc00 = __builtin_amdgcn_mfma_f32_32x32x16_bf16(a0, b0, acc00, 0, 0, 0);
            acc01 = __builtin_amdgcn_mfma_f32_32x32x16_bf16(a0, b1, acc01, 0, 0, 0);
            acc10 = __builtin_amdgcn_mfma_f32_32x32x16_bf16(a1, b0, acc10, 0, 0, 0);
            acc11 = __builtin_amdgcn_mfma_f32_32x32x16_bf16(a1, b1, acc11, 0, 0, 0);
        }
        __syncthreads();
    }

    int mbase = m0 + wm * 64, nbase = n0 + wn * 64;
    float bia0 = b1[nbase + c], bia1 = b1[nbase + 32 + c];
#pragma unroll
    for (int mi = 0; mi < 2; ++mi) {
        const floatx16& A0 = mi ? acc10 : acc00;
        const floatx16& A1 = mi ? acc11 : acc01;
#pragma unroll
        for (int r = 0; r < 16; ++r) {
            int m = mbase + mi * 32 + (r & 3) + 8 * (r >> 2) + 4 * h;
            C[(size_t)m * D + nbase + c] = __float2bfloat16(A0[r] + bia0);
            C[(size_t)m * D + nbase + 32 + c] = __float2bfloat16(A1[r] + bia1);
        }
    }
}

// ---------------- K2: MFMA score einsum + sigmoid + dual max ---------------
// v2: K fragments load DIRECTLY global->VGPR (each K row used by exactly one
// wave once per block -> LDS round-trip was pure overhead). Only Q (shared by
// all 4 waves) goes through LDS, double-buffered, staged one K-step ahead.
// One barrier per K-step. LDS reads halve, LDS writes drop 5x.
__global__ __launch_bounds__(256, 3) void k_score_mfma(
        const __hip_bfloat16* __restrict__ QKb, const float* __restrict__ sig,
        float* __restrict__ xbuf) {
    __shared__ __attribute__((aligned(16))) unsigned short lds[2 * 64 * 64]; // 16 KB: Q dbuf, then sig
    const unsigned short* QKu = reinterpret_cast<const unsigned short*>(QKb);

    int tid = threadIdx.x;
    int w = tid >> 6;
    int l = tid & 63;
    int h = l >> 5;
    int c = l & 31;
    int chg = (l & 7) ^ (l >> 3);     // swizzled source chunk for Q staging
    int cx = c & 7;

    int qi = blockIdx.x >> 6;
    int kg = blockIdx.x & 63;

    // Q staging sources: j in {0,1} covers rows j*32 + w*8 + (l>>3)
    const unsigned short* qsrc0 = QKu + (size_t)(qi * 64 +      w * 8 + (l >> 3)) * D + chg * 8;
    const unsigned short* qsrc1 = QKu + (size_t)(qi * 64 + 32 + w * 8 + (l >> 3)) * D + chg * 8;
    unsigned short* dst0 = lds + (w * 8) * 64;        // + buf*4096
    unsigned short* dst1 = lds + (32 + w * 8) * 64;

    // K fragment sources (direct to registers): lane (h,c) -> row c / row 32+c,
    // k elems kb*64 + st*16 + h*8 (byte offsets <= 992, fold into imm)
    const unsigned short* kp0 = QKu + (size_t)(NQ * SSZ + (kg * 4 + w) * 64 + c) * D + h * 8;
    const unsigned short* kp1 = kp0 + (size_t)32 * D;

    floatx16 acc00 = {}, acc01 = {}, acc10 = {}, acc11 = {};
    bf16x8 ka0[2][4], ka1[2][4];      // [kstep&1][st]

    // prologue: stage Q step 0, load K frags step 0
    gl2lds16(qsrc0, dst0);
    gl2lds16(qsrc1, dst1);
#pragma unroll
    for (int st = 0; st < 4; ++st) {
        ka0[0][st] = *reinterpret_cast<const bf16x8*>(kp0 + st * 16);
        ka1[0][st] = *reinterpret_cast<const bf16x8*>(kp1 + st * 16);
    }
    __syncthreads();

#pragma unroll
    for (int kbi = 0; kbi < 8; ++kbi) {
        const int cur = kbi & 1, nxt = cur ^ 1;
        if (kbi < 7) {
            // issue next step's Q staging + K register loads; they fly under
            // this step's MFMAs and drain at the end-of-step barrier.
            gl2lds16(qsrc0 + (kbi + 1) * 64, dst0 + nxt * 4096);
            gl2lds16(qsrc1 + (kbi + 1) * 64, dst1 + nxt * 4096);
#pragma unroll
            for (int st = 0; st < 4; ++st) {
                ka0[nxt][st] = *reinterpret_cast<const bf16x8*>(kp0 + (kbi + 1) * 64 + st * 16);
                ka1[nxt][st] = *reinterpret_cast<const bf16x8*>(kp1 + (kbi + 1) * 64 + st * 16);
            }
        }
        const unsigned short* ldsQ = lds + cur * 4096;
#pragma unroll
        for (int st = 0; st < 4; ++st) {
            int ko = ((st * 2 + h) ^ cx) * 8;
            bf16x8 b0 = *reinterpret_cast<const bf16x8*>(ldsQ + c * 64 + ko);
            bf16x8 b1 = *reinterpret_cast<const bf16x8*>(ldsQ + (32 + c) * 64 + ko);
            acc00 = __builtin_amdgcn_mfma_f32_32x32x16_bf16(ka0[cur][st], b0, acc00, 0, 0, 0);
            acc01 = __builtin_amdgcn_mfma_f32_32x32x16_bf16(ka0[cur][st], b1, acc01, 0, 0, 0);
            acc10 = __builtin_amdgcn_mfma_f32_32x32x16_bf16(ka1[cur][st], b0, acc10, 0, 0, 0);
            acc11 = __builtin_amdgcn_mfma_f32_32x32x16_bf16(ka1[cur][st], b1, acc11, 0, 0, 0);
        }
        __syncthreads();  // protects buf[nxt] (now staged) and buf[cur] (about to be re-staged)
    }

    float* sigl = reinterpret_cast<float*>(lds);
#pragma unroll
    for (int i = 0; i < 4; ++i) {
        int idx = i * 256 + tid;
        *reinterpret_cast<float4*>(sigl + idx * 4) =
            *reinterpret_cast<const float4*>(sig + idx * 4);
    }
    __syncthreads();

    int p = qi * 256 + kg * 4 + w;
    float tmax0 = -FLT_MAX, tmax1 = -FLT_MAX;
    float smax[2][16];
#pragma unroll
    for (int si = 0; si < 2; ++si) {
        const floatx16& A0 = si ? acc10 : acc00;
        const floatx16& A1 = si ? acc11 : acc01;
#pragma unroll
        for (int r = 0; r < 16; ++r) {
            int srow = si * 32 + (r & 3) + 8 * (r >> 2) + 4 * h;
            float v0 = A0[r] * sigl[srow * 64 + c];
            float v1 = A1[r] * sigl[srow * 64 + 32 + c];
            tmax0 = fmaxf(tmax0, v0);
            tmax1 = fmaxf(tmax1, v1);
            smax[si][r] = fmaxf(v0, v1);
        }
    }
    tmax0 = fmaxf(tmax0, __shfl_xor(tmax0, 32, 64));
    tmax1 = fmaxf(tmax1, __shfl_xor(tmax1, 32, 64));
    if (h == 0) {
        xbuf[(size_t)(2 * p) * 64 + c] = tmax0;
        xbuf[(size_t)(2 * p) * 64 + 32 + c] = tmax1;
    }
#pragma unroll
    for (int stage = 1; stage < 32; stage <<= 1) {
#pragma unroll
        for (int si = 0; si < 2; ++si)
#pragma unroll
            for (int r = 0; r < 16; ++r)
                smax[si][r] = fmaxf(smax[si][r], __shfl_xor(smax[si][r], stage, 64));
    }
    if (c == 0) {
#pragma unroll
        for (int si = 0; si < 2; ++si)
#pragma unroll
            for (int r = 0; r < 16; ++r) {
                int srow = si * 32 + (r & 3) + 8 * (r >> 2) + 4 * h;
                xbuf[(size_t)(2 * p + 1) * 64 + srow] = smax[si][r];
            }
    }
}

// ---------------- K3: row stats S1[64], S2[64][64] over xbuf ---------------
__global__ __launch_bounds__(256) void k_stats1(const float* __restrict__ xbuf,
        double* __restrict__ S1d, double* __restrict__ S2d) {
    __shared__ float xr[4][64];
    int tid = threadIdx.x;
    int row0 = blockIdx.x * 256;
    float acc[16] = {};
    float s1 = 0.f;
    int pbase = tid * 16;
    for (int it = 0; it < 64; ++it) {
        int r = row0 + it * 4;
        xr[tid >> 6][tid & 63] = xbuf[(size_t)(r + (tid >> 6)) * 64 + (tid & 63)];
        __syncthreads();
#pragma unroll
        for (int e = 0; e < 16; ++e) {
            int a = (pbase + e) >> 6, b = (pbase + e) & 63;
            acc[e] += xr[0][a] * xr[0][b] + xr[1][a] * xr[1][b]
                    + xr[2][a] * xr[2][b] + xr[3][a] * xr[3][b];
        }
        if (tid < 64) s1 += xr[0][tid] + xr[1][tid] + xr[2][tid] + xr[3][tid];
        __syncthreads();
    }
#pragma unroll
    for (int e = 0; e < 16; ++e) atomicAdd(&S2d[pbase + e], (double)acc[e]);
    if (tid < 64) atomicAdd(&S1d[tid], (double)s1);
}

// ---------------- K4: finalize BN1 + normalized mean/cov -------------------
__global__ __launch_bounds__(256) void k_fin1(
        const double* __restrict__ S1d, const double* __restrict__ S2d,
        const float* __restrict__ g1, const float* __restrict__ be1,
        float* __restrict__ bn1, float* __restrict__ xbarn, float* __restrict__ covn) {
    int tid = threadIdx.x;
    double sum = 0.0, sumsq = 0.0;
    for (int j = 0; j < 64; ++j) { sum += S1d[j]; sumsq += S2d[j * 64 + j]; }
    const double Nall = (double)ROWSX * 64.0;
    double m1 = sum / Nall;
    double var1 = sumsq / Nall - m1 * m1;
    double scaled = (double)g1[0] / sqrt(var1 + 1e-5);
    if (tid == 0) { bn1[0] = (float)m1; bn1[1] = (float)scaled; }
    const double Rinv = 1.0 / (double)ROWSX;
    if (tid < 64) xbarn[tid] = (float)((S1d[tid] * Rinv - m1) * scaled) + be1[0];
#pragma unroll
    for (int e = 0; e < 16; ++e) {
        int idx = tid * 16 + e;
        int a = idx >> 6, b = idx & 63;
        double cov = S2d[idx] * Rinv - (S1d[a] * Rinv) * (S1d[b] * Rinv);
        covn[idx] = (float)(cov * scaled * scaled);
    }
}

// ---------------- K5: analytic BN2 constants per feature -------------------
__global__ __launch_bounds__(64) void k_bn2(
        const float* __restrict__ covn, const float* __restrict__ xbarn,
        const __hip_bfloat16* __restrict__ W2b,
        const float* __restrict__ g2, const float* __restrict__ be2,
        float* __restrict__ alpha, float* __restrict__ beta) {
    int f = blockIdx.x;
    int j = threadIdx.x;
    float wj = __bfloat162float(W2b[(size_t)f * 64 + j]);
    float t1 = 0.f;
    for (int b = 0; b < 64; ++b)
        t1 += covn[j * 64 + b] * __bfloat162float(W2b[(size_t)f * 64 + b]);
    float vc = wj * t1;
    float mc = wj * xbarn[j];
#pragma unroll
    for (int off = 32; off; off >>= 1) {
        vc += __shfl_down(vc, off);
        mc += __shfl_down(mc, off);
    }
    if (j == 0) {
        float t2 = g2[f] * rsqrtf(vc + 1e-5f);
        alpha[f] = t2;
        beta[f] = -t2 * mc + be2[f];
    }
}

// ---------------- K6: MFMA MLP: u = bf16(x_n) @ W2b^T, z = sum relu(a*u+b)*w3
__global__ __launch_bounds__(256, 2) void k_mlp_mfma(
        const float* __restrict__ xbuf, const float* __restrict__ bn1,
        const float* __restrict__ be1, const __hip_bfloat16* __restrict__ W2b,
        const float* __restrict__ alpha, const float* __restrict__ beta,
        const float* __restrict__ W3, const float* __restrict__ b3,
        float* __restrict__ z) {
    constexpr int LDR = 72;
    __shared__ __attribute__((aligned(16))) unsigned short Xs[128 * LDR];
    __shared__ __attribute__((aligned(16))) unsigned short Ws[128 * LDR];
    __shared__ float abw[3 * 128];
    const unsigned short* W2u = reinterpret_cast<const unsigned short*>(W2b);
    int tid = threadIdx.x;
    int w = tid >> 6, l = tid & 63, h = l >> 5, c = l & 31;
    int r0 = blockIdx.x * 128;
    float m1 = bn1[0], sc = bn1[1], sh = be1[0];

#pragma unroll
    for (int i = 0; i < 4; ++i) {
        int id = i * 256 + tid;
        int row = id >> 3, cg = id & 7;
        const float* src = xbuf + (size_t)(r0 + row) * 64 + cg * 8;
        float4 v0 = *reinterpret_cast<const float4*>(src);
        float4 v1 = *reinterpret_cast<const float4*>(src + 4);
        union { __hip_bfloat16 hh[8]; uint4 u; } o;
        o.hh[0] = __float2bfloat16((v0.x - m1) * sc + sh);
        o.hh[1] = __float2bfloat16((v0.y - m1) * sc + sh);
        o.hh[2] = __float2bfloat16((v0.z - m1) * sc + sh);
        o.hh[3] = __float2bfloat16((v0.w - m1) * sc + sh);
        o.hh[4] = __float2bfloat16((v1.x - m1) * sc + sh);
        o.hh[5] = __float2bfloat16((v1.y - m1) * sc + sh);
        o.hh[6] = __float2bfloat16((v1.z - m1) * sc + sh);
        o.hh[7] = __float2bfloat16((v1.w - m1) * sc + sh);
        *reinterpret_cast<uint4*>(&Xs[row * LDR + cg * 8]) = o.u;
    }

    float zacc[16] = {};
    for (int fc = 0; fc < FF / 128; ++fc) {
#pragma unroll
        for (int i = 0; i < 4; ++i) {
            int id = i * 256 + tid;
            int row = id >> 3, cg = id & 7;
            uint4 v = *reinterpret_cast<const uint4*>(W2u + (size_t)(fc * 128 + row) * 64 + cg * 8);
            *reinterpret_cast<uint4*>(&Ws[row * LDR + cg * 8]) = v;
        }
        if (tid < 128) {
            int f = fc * 128 + tid;
            abw[tid] = alpha[f];
            abw[128 + tid] = beta[f];
            abw[256 + tid] = W3[f];
        }
        __syncthreads();
        bf16x8 a[4];
#pragma unroll
        for (int st = 0; st < 4; ++st)
            a[st] = *reinterpret_cast<const bf16x8*>(&Xs[(w * 32 + c) * LDR + st * 16 + h * 8]);
#pragma unroll
        for (int nq = 0; nq < 4; ++nq) {
            floatx16 u = {};
#pragma unroll
            for (int st = 0; st < 4; ++st) {
                bf16x8 b = *reinterpret_cast<const bf16x8*>(&Ws[(nq * 32 + c) * LDR + st * 16 + h * 8]);
                u = __builtin_amdgcn_mfma_f32_32x32x16_bf16(a[st], b, u, 0, 0, 0);
            }
            float al = abw[nq * 32 + c];
            float bt = abw[128 + nq * 32 + c];
            float w3 = abw[256 + nq * 32 + c];
#pragma unroll
            for (int r = 0; r < 16; ++r)
                zacc[r] += fmaxf(al * u[r] + bt, 0.f) * w3;
        }
        __syncthreads();
    }
#pragma unroll
    for (int stage = 1; stage < 32; stage <<= 1)
#pragma unroll
        for (int r = 0; r < 16; ++r)
            zacc[r] += __shfl_xor(zacc[r], stage, 64);
    if (c == 0) {
        float bb = b3[0];
#pragma unroll
        for (int r = 0; r < 16; ++r) {
            int row = r0 + w * 32 + (r & 3) + 8 * (r >> 2) + 4 * h;
            z[row] = zacc[r] + bb;
        }
    }
}

// ---------------- K7: pair-sum + BN3 stats ---------------------------------
__global__ __launch_bounds__(256) void k_pair(const float* __restrict__ z,
        float* __restrict__ v, double* __restrict__ sums3) {
    int i = blockIdx.x * 256 + threadIdx.x;
    float val = z[2 * i] + z[2 * i + 1];
    v[i] = val;
    float s = val, ss = val * val;
#pragma unroll
    for (int off = 32; off; off >>= 1) {
        s += __shfl_down(s, off);
        ss += __shfl_down(ss, off);
    }
    __shared__ float bs[4], bss[4];
    int lane = threadIdx.x & 63, w = threadIdx.x >> 6;
    if (lane == 0) { bs[w] = s; bss[w] = ss; }
    __syncthreads();
    if (threadIdx.x == 0) {
        atomicAdd(&sums3[0], (double)(bs[0] + bs[1] + bs[2] + bs[3]));
        atomicAdd(&sums3[1], (double)(bss[0] + bss[1] + bss[2] + bss[3]));
    }
}

// ---------------- K8: finalize BN3 -----------------------------------------
__global__ void k_fin3(const double* __restrict__ sums3, const float* __restrict__ g3,
                       float* __restrict__ bn3) {
    double m = sums3[0] / (double)PAIRS;
    double var = sums3[1] / (double)PAIRS - m * m;
    bn3[0] = (float)m;
    bn3[1] = (float)((double)g3[0] / sqrt(var + 1e-5));
}

// ---------------- K9: write output -----------------------------------------
__global__ void k_out(const float* __restrict__ v, const float* __restrict__ bn3,
                      const float* __restrict__ be3, float* __restrict__ out) {
    int i = blockIdx.x * 256 + threadIdx.x;
    if (i < PAIRS) out[i] = (v[i] - bn3[0]) * bn3[1] + be3[0];
}

extern "C" void kernel_launch(void* const* d_in, const int* in_sizes, int n_in,
                              void* d_out, int out_size, void* d_ws, size_t ws_size,
                              hipStream_t stream) {
    (void)in_sizes; (void)n_in; (void)out_size; (void)ws_size;
    const float* tgt = (const float*)d_in[0];
    const float* mem = (const float*)d_in[1];
    const float* W1  = (const float*)d_in[2];
    const float* b1  = (const float*)d_in[3];
    const float* se  = (const float*)d_in[4];
    const float* W2  = (const float*)d_in[5];
    const float* b2  = (const float*)d_in[6];
    const float* W3  = (const float*)d_in[7];
    const float* b3  = (const float*)d_in[8];
    const float* g1  = (const float*)d_in[9];
    const float* be1 = (const float*)d_in[10];
    const float* g2  = (const float*)d_in[11];
    const float* be2 = (const float*)d_in[12];
    const float* g3  = (const float*)d_in[13];
    const float* be3 = (const float*)d_in[14];
    const int*  flag = (const int*)d_in[15];
    (void)b2;  // cancels analytically through BN2's mean-subtract
    float* out = (float*)d_out;

    char* ws = (char*)d_ws;
    size_t off = 0;
    auto alloc = [&](size_t bytes) -> void* {
        void* p = ws + off;
        off = (off + bytes + 255) & ~(size_t)255;
        return p;
    };
    float* sig   = (float*)alloc((size_t)SSZ * SSZ * 4);
    __hip_bfloat16* Xb  = (__hip_bfloat16*)alloc((size_t)NX * D * 2);   // 21 MB
    __hip_bfloat16* W1b = (__hip_bfloat16*)alloc((size_t)D * D * 2);    // 0.5 MB
    __hip_bfloat16* W2b = (__hip_bfloat16*)alloc((size_t)FF * 64 * 2);  // 0.25 MB
    __hip_bfloat16* QKb = (__hip_bfloat16*)alloc((size_t)NX * D * 2);   // 21 MB
    float* xbuf  = (float*)alloc((size_t)ROWSX * 64 * 4);               // 8 MB
    float* z     = (float*)alloc((size_t)ROWSX * 4);
    float* v     = (float*)alloc((size_t)PAIRS * 4);
    float* alpha = (float*)alloc((size_t)FF * 4);
    float* beta  = (float*)alloc((size_t)FF * 4);
    float* xbarn = (float*)alloc(64 * 4);
    float* covn  = (float*)alloc(64 * 64 * 4);
    float* bn1   = (float*)alloc(16);
    float* bn3   = (float*)alloc(16);
    size_t statsStart = off;
    double* S1d   = (double*)alloc(64 * 8);
    double* S2d   = (double*)alloc(64 * 64 * 8);
    double* sums3 = (double*)alloc(2 * 8);
    size_t statsEnd = off;

    hipMemsetAsync(ws + statsStart, 0, statsEnd - statsStart, stream);

    k_sig<<<16, 256, 0, stream>>>(se, flag, sig);
    constexpr int CVT4 = (NX * D + D * D + FF * 64) / 4;
    k_cvt<<<(CVT4 + 255) / 256, 256, 0, stream>>>(tgt, mem, W1, W2, Xb, W1b, W2b);
    k_gemm1_mfma<<<(NX / 128) * (D / 128), 256, 0, stream>>>(Xb, W1b, b1, flag, QKb);
    k_score_mfma<<<NQ * (NK / 4), 256, 0, stream>>>(QKb, sig, xbuf);
    k_stats1<<<128, 256, 0, stream>>>(xbuf, S1d, S2d);
    k_fin1<<<1, 256, 0, stream>>>(S1d, S2d, g1, be1, bn1, xbarn, covn);
    k_bn2<<<FF, 64, 0, stream>>>(covn, xbarn, W2b, g2, be2, alpha, beta);
    k_mlp_mfma<<<ROWSX / 128, 256, 0, stream>>>(xbuf, bn1, be1, W2b, alpha, beta, W3, b3, z);
    k_pair<<<PAIRS / 256, 256, 0, stream>>>(z, v, sums3);
    k_fin3<<<1, 1, 0, stream>>>(sums3, g3, bn3);
    k_out<<<PAIRS / 256, 256, 0, stream>>>(v, bn3, be3, out);
}

// Round 2
// 369.517 us; speedup vs baseline: 1.0610x; 1.0610x over previous
//
#include <hip/hip_runtime.h>
#include <hip/hip_bf16.h>
#include <math.h>
#include <float.h>

// dims
constexpr int NQ = 64, NK = 256, SSZ = 64, D = 512, FF = 2048;
constexpr int PAIRS = NQ * NK;          // 16384
constexpr int ROWSX = 2 * PAIRS;        // 32768
constexpr int NX = (NQ + NK) * SSZ;     // 20480 rows of X = [tgt;mem]

typedef __bf16 bf16x8 __attribute__((ext_vector_type(8)));
typedef float floatx16 __attribute__((ext_vector_type(16)));

// async global->LDS, 16 B per lane; LDS dest = wave-uniform base + lane*16
__device__ __forceinline__ void gl2lds16(const unsigned short* g, unsigned short* l) {
    __builtin_amdgcn_global_load_lds(
        (const __attribute__((address_space(1))) unsigned int*)(g),
        (__attribute__((address_space(3))) unsigned int*)(l),
        16, 0, 0);
}

// Fragment layout for QKf: block (rg, kgrp) = 1 KB at ((rg*32 + kgrp)*1024):
//   lane l (16 B entry at l*16) holds row rg*32 + (l&31),
//   k elems kgrp*16 + (l>>5)*8 .. +7  == exactly the 32x32x16 A/B fragment.

// ---------------- K0: sigmoid of score_embed (or 1.0 if !flag) -------------
__global__ void k_sig(const float* __restrict__ se, const int* __restrict__ flag,
                      float* __restrict__ sig) {
    int i = blockIdx.x * blockDim.x + threadIdx.x;
    if (i < SSZ * SSZ) {
        sig[i] = (*flag) ? 1.0f / (1.0f + expf(-se[i])) : 1.0f;
    }
}

// ---------------- K0b: convert X=[tgt;mem], W1, W2 to bf16 -----------------
__global__ __launch_bounds__(256) void k_cvt(
        const float* __restrict__ tgt, const float* __restrict__ mem,
        const float* __restrict__ W1, const float* __restrict__ W2,
        __hip_bfloat16* __restrict__ Xb, __hip_bfloat16* __restrict__ W1b,
        __hip_bfloat16* __restrict__ W2b) {
    constexpr int T4 = NQ * SSZ * D / 4;   // tgt float4 count
    constexpr int X4 = NX * D / 4;         // X float4 count
    constexpr int W4 = D * D / 4;          // W1 float4 count
    constexpr int V4 = FF * 64 / 4;        // W2 float4 count
    int idx = blockIdx.x * 256 + threadIdx.x;
    if (idx >= X4 + W4 + V4) return;
    const float* src;
    __hip_bfloat16* dst;
    if (idx < T4)           { src = tgt + (size_t)idx * 4;             dst = Xb + (size_t)idx * 4; }
    else if (idx < X4)      { src = mem + (size_t)(idx - T4) * 4;      dst = Xb + (size_t)idx * 4; }
    else if (idx < X4 + W4) { src = W1 + (size_t)(idx - X4) * 4;       dst = W1b + (size_t)(idx - X4) * 4; }
    else                    { src = W2 + (size_t)(idx - X4 - W4) * 4;  dst = W2b + (size_t)(idx - X4 - W4) * 4; }
    float4 v = *reinterpret_cast<const float4*>(src);
    union { __hip_bfloat16 h[4]; uint2 u; } o;
    o.h[0] = __float2bfloat16(v.x); o.h[1] = __float2bfloat16(v.y);
    o.h[2] = __float2bfloat16(v.z); o.h[3] = __float2bfloat16(v.w);
    *reinterpret_cast<uint2*>(dst) = o.u;
}

// ---------------- K1: MFMA GEMM1: QKf = frag(Xb @ W1b^T + b1) --------------
// Swapped-operand MFMA (acc rows = W1 rows n, cols = X rows m) so each thread
// holds 4 consecutive n per reg-quad -> packed 8 B stores directly into the
// fragment layout. Main-loop staging identical to the proven v0 kernel.
__global__ __launch_bounds__(256, 3) void k_gemm1_mfma(
        const __hip_bfloat16* __restrict__ Xb, const __hip_bfloat16* __restrict__ W1b,
        const float* __restrict__ b1, const int* __restrict__ flag,
        __hip_bfloat16* __restrict__ QKf) {
    __shared__ __attribute__((aligned(16))) unsigned short lds[2 * 128 * 64]; // 32 KB
    const unsigned short* Xu = reinterpret_cast<const unsigned short*>(Xb);
    const unsigned short* Wu = reinterpret_cast<const unsigned short*>(W1b);
    unsigned short* Fu = reinterpret_cast<unsigned short*>(QKf);

    int tid = threadIdx.x;
    int bm = blockIdx.x >> 2, bn = blockIdx.x & 3;
    int m0 = bm * 128, n0 = bn * 128;

    if (!(*flag)) {
        // copy X rows into fragment layout (correctness path, flag==0 only)
#pragma unroll
        for (int i = 0; i < 8; ++i) {
            int e = i * 256 + tid;          // 0..2047 entries of 16 B
            int fb = e >> 6;                // frag block 0..31
            int lp = e & 63;                // lane entry
            int rgl = fb >> 3, kgl = fb & 7;
            int row = m0 + rgl * 32 + (lp & 31);
            int col = n0 + kgl * 16 + (lp >> 5) * 8;
            uint4 v = *reinterpret_cast<const uint4*>(Xu + (size_t)row * D + col);
            size_t ofs = ((size_t)((m0 >> 5) + rgl) * 32 + (n0 >> 4) + kgl) * 512 + lp * 8;
            *reinterpret_cast<uint4*>(Fu + ofs) = v;
        }
        return;
    }

    int w = tid >> 6, l = tid & 63, h = l >> 5, c = l & 31;
    int wm = w >> 1, wn = w & 1;
    int chg = (l & 7) ^ (l >> 3);     // swizzled source chunk for this lane
    int cx = c & 7;
    // acc[ni][mi]: n-half ni (W rows), m-half mi (X rows)
    floatx16 acc00 = {}, acc01 = {}, acc10 = {}, acc11 = {};

    for (int kb = 0; kb < D; kb += 64) {
#pragma unroll
        for (int j = 0; j < 8; ++j) {
            int i = w * 8 + j;              // 0..31
            int buf = i >> 4;               // 0: A(X), 1: B(W1)
            int rb = (i & 15) * 8;
            int r = rb + (l >> 3);
            const unsigned short* src = (buf == 0)
                ? (Xu + (size_t)(m0 + r) * D + kb + chg * 8)
                : (Wu + (size_t)(n0 + r) * D + kb + chg * 8);
            gl2lds16(src, lds + buf * 8192 + rb * 64);
        }
        __syncthreads();
        const unsigned short* pA = lds + (wm * 64) * 64;
        const unsigned short* pB = lds + 8192 + (wn * 64) * 64;
#pragma unroll
        for (int st = 0; st < 4; ++st) {
            int ko = ((st * 2 + h) ^ cx) * 8;
            bf16x8 a0 = *reinterpret_cast<const bf16x8*>(pA + c * 64 + ko);
            bf16x8 a1 = *reinterpret_cast<const bf16x8*>(pA + (32 + c) * 64 + ko);
            bf16x8 b0 = *reinterpret_cast<const bf16x8*>(pB + c * 64 + ko);
            bf16x8 b1v = *reinterpret_cast<const bf16x8*>(pB + (32 + c) * 64 + ko);
            acc00 = __builtin_amdgcn_mfma_f32_32x32x16_bf16(b0, a0, acc00, 0, 0, 0);
            acc01 = __builtin_amdgcn_mfma_f32_32x32x16_bf16(b0, a1, acc01, 0, 0, 0);
            acc10 = __builtin_amdgcn_mfma_f32_32x32x16_bf16(b1v, a0, acc10, 0, 0, 0);
            acc11 = __builtin_amdgcn_mfma_f32_32x32x16_bf16(b1v, a1, acc11, 0, 0, 0);
        }
        __syncthreads();
    }

    // epilogue: n = nb + 8g + 4h + q (q=0..3 consecutive -> 8 B pack), m = mb + c
    // frag store: rg = mb>>5, kgrp = (nb>>4) + (g>>1), lane' = c + 32*(g&1), byte 8h
#pragma unroll
    for (int ni = 0; ni < 2; ++ni) {
        int nb = n0 + wn * 64 + ni * 32;
#pragma unroll
        for (int mi = 0; mi < 2; ++mi) {
            const floatx16& A = ni ? (mi ? acc11 : acc10) : (mi ? acc01 : acc00);
            int mb = m0 + wm * 64 + mi * 32;
            size_t rgbase = ((size_t)(mb >> 5) * 32 + (nb >> 4)) * 512;
#pragma unroll
            for (int g = 0; g < 4; ++g) {
                float4 bia = *reinterpret_cast<const float4*>(&b1[nb + 8 * g + 4 * h]);
                union { __hip_bfloat16 hh[4]; uint2 u; } o;
                o.hh[0] = __float2bfloat16(A[4 * g + 0] + bia.x);
                o.hh[1] = __float2bfloat16(A[4 * g + 1] + bia.y);
                o.hh[2] = __float2bfloat16(A[4 * g + 2] + bia.z);
                o.hh[3] = __float2bfloat16(A[4 * g + 3] + bia.w);
                *reinterpret_cast<uint2*>(Fu + rgbase + (size_t)(g >> 1) * 512
                                          + (c + 32 * (g & 1)) * 8 + 4 * h) = o.u;
            }
        }
    }
}

// ---------------- K2: MFMA score einsum + sigmoid + dual max ---------------
// v3: ALL operands load as coalesced dwordx4 fragments straight from the
// pre-fragmented QKf -> no operand LDS, no barriers in the K loop. sig is
// staged to LDS via global_load_lds under the K loop (one barrier total).
__global__ __launch_bounds__(256, 2) void k_score_mfma(
        const __hip_bfloat16* __restrict__ QKf, const float* __restrict__ sig,
        float* __restrict__ xbuf) {
    __shared__ __attribute__((aligned(16))) unsigned short lds[64 * 64 * 2]; // 16 KB (sig)
    const unsigned short* Fu = reinterpret_cast<const unsigned short*>(QKf);
    const unsigned short* sigu = reinterpret_cast<const unsigned short*>(sig);

    int tid = threadIdx.x;
    int w = tid >> 6, l = tid & 63, h = l >> 5, c = l & 31;
    int qi = blockIdx.x >> 6, kg = blockIdx.x & 63;

    // stage sig (16 KB) into LDS; flies under the whole K loop
#pragma unroll
    for (int j = 0; j < 4; ++j) {
        int blk = w * 4 + j;
        gl2lds16(sigu + blk * 512 + l * 8, lds + blk * 512);
    }

    // fragment pointers (each load = 1 KB contiguous across the wave)
    const unsigned short* pKA = Fu + ((size_t)(128 + (kg * 4 + w) * 2) * 32) * 512 + l * 8;
    const unsigned short* pKB = pKA + 32 * 512;
    const unsigned short* pQ0 = Fu + ((size_t)(qi * 2) * 32) * 512 + l * 8;
    const unsigned short* pQ1 = pQ0 + 32 * 512;

    floatx16 acc00 = {}, acc01 = {}, acc10 = {}, acc11 = {};
    bf16x8 ka0[2][4], ka1[2][4], qb0[2][4], qb1[2][4];
#pragma unroll
    for (int st = 0; st < 4; ++st) {
        ka0[0][st] = *reinterpret_cast<const bf16x8*>(pKA + st * 512);
        ka1[0][st] = *reinterpret_cast<const bf16x8*>(pKB + st * 512);
        qb0[0][st] = *reinterpret_cast<const bf16x8*>(pQ0 + st * 512);
        qb1[0][st] = *reinterpret_cast<const bf16x8*>(pQ1 + st * 512);
    }
#pragma unroll
    for (int kbi = 0; kbi < 8; ++kbi) {
        const int cur = kbi & 1, nxt = cur ^ 1;
        if (kbi < 7) {
            pKA += 4 * 512; pKB += 4 * 512; pQ0 += 4 * 512; pQ1 += 4 * 512;
#pragma unroll
            for (int st = 0; st < 4; ++st) {
                ka0[nxt][st] = *reinterpret_cast<const bf16x8*>(pKA + st * 512);
                ka1[nxt][st] = *reinterpret_cast<const bf16x8*>(pKB + st * 512);
                qb0[nxt][st] = *reinterpret_cast<const bf16x8*>(pQ0 + st * 512);
                qb1[nxt][st] = *reinterpret_cast<const bf16x8*>(pQ1 + st * 512);
            }
        }
#pragma unroll
        for (int st = 0; st < 4; ++st) {
            acc00 = __builtin_amdgcn_mfma_f32_32x32x16_bf16(ka0[cur][st], qb0[cur][st], acc00, 0, 0, 0);
            acc01 = __builtin_amdgcn_mfma_f32_32x32x16_bf16(ka0[cur][st], qb1[cur][st], acc01, 0, 0, 0);
            acc10 = __builtin_amdgcn_mfma_f32_32x32x16_bf16(ka1[cur][st], qb0[cur][st], acc10, 0, 0, 0);
            acc11 = __builtin_amdgcn_mfma_f32_32x32x16_bf16(ka1[cur][st], qb1[cur][st], acc11, 0, 0, 0);
        }
    }

    __syncthreads();  // sig staged (vmcnt drained) before epilogue reads
    float* sigl = reinterpret_cast<float*>(lds);

    int p = qi * 256 + kg * 4 + w;
    float tmax0 = -FLT_MAX, tmax1 = -FLT_MAX;
    float smax[2][16];
#pragma unroll
    for (int si = 0; si < 2; ++si) {
        const floatx16& A0 = si ? acc10 : acc00;
        const floatx16& A1 = si ? acc11 : acc01;
#pragma unroll
        for (int r = 0; r < 16; ++r) {
            int srow = si * 32 + (r & 3) + 8 * (r >> 2) + 4 * h;
            float v0 = A0[r] * sigl[srow * 64 + c];
            float v1 = A1[r] * sigl[srow * 64 + 32 + c];
            tmax0 = fmaxf(tmax0, v0);
            tmax1 = fmaxf(tmax1, v1);
            smax[si][r] = fmaxf(v0, v1);
        }
    }
    tmax0 = fmaxf(tmax0, __shfl_xor(tmax0, 32, 64));
    tmax1 = fmaxf(tmax1, __shfl_xor(tmax1, 32, 64));
    if (h == 0) {
        xbuf[(size_t)(2 * p) * 64 + c] = tmax0;
        xbuf[(size_t)(2 * p) * 64 + 32 + c] = tmax1;
    }
#pragma unroll
    for (int stage = 1; stage < 32; stage <<= 1) {
#pragma unroll
        for (int si = 0; si < 2; ++si)
#pragma unroll
            for (int r = 0; r < 16; ++r)
                smax[si][r] = fmaxf(smax[si][r], __shfl_xor(smax[si][r], stage, 64));
    }
    if (c == 0) {
#pragma unroll
        for (int si = 0; si < 2; ++si)
#pragma unroll
            for (int r = 0; r < 16; ++r) {
                int srow = si * 32 + (r & 3) + 8 * (r >> 2) + 4 * h;
                xbuf[(size_t)(2 * p + 1) * 64 + srow] = smax[si][r];
            }
    }
}

// ---------------- K3: row stats S1[64], S2[64][64] over xbuf ---------------
__global__ __launch_bounds__(256) void k_stats1(const float* __restrict__ xbuf,
        double* __restrict__ S1d, double* __restrict__ S2d) {
    __shared__ float xr[4][64];
    int tid = threadIdx.x;
    int row0 = blockIdx.x * 256;
    float acc[16] = {};
    float s1 = 0.f;
    int pbase = tid * 16;
    for (int it = 0; it < 64; ++it) {
        int r = row0 + it * 4;
        xr[tid >> 6][tid & 63] = xbuf[(size_t)(r + (tid >> 6)) * 64 + (tid & 63)];
        __syncthreads();
#pragma unroll
        for (int e = 0; e < 16; ++e) {
            int a = (pbase + e) >> 6, b = (pbase + e) & 63;
            acc[e] += xr[0][a] * xr[0][b] + xr[1][a] * xr[1][b]
                    + xr[2][a] * xr[2][b] + xr[3][a] * xr[3][b];
        }
        if (tid < 64) s1 += xr[0][tid] + xr[1][tid] + xr[2][tid] + xr[3][tid];
        __syncthreads();
    }
#pragma unroll
    for (int e = 0; e < 16; ++e) atomicAdd(&S2d[pbase + e], (double)acc[e]);
    if (tid < 64) atomicAdd(&S1d[tid], (double)s1);
}

// ---------------- K4: finalize BN1 + normalized mean/cov -------------------
__global__ __launch_bounds__(256) void k_fin1(
        const double* __restrict__ S1d, const double* __restrict__ S2d,
        const float* __restrict__ g1, const float* __restrict__ be1,
        float* __restrict__ bn1, float* __restrict__ xbarn, float* __restrict__ covn) {
    int tid = threadIdx.x;
    double sum = 0.0, sumsq = 0.0;
    for (int j = 0; j < 64; ++j) { sum += S1d[j]; sumsq += S2d[j * 64 + j]; }
    const double Nall = (double)ROWSX * 64.0;
    double m1 = sum / Nall;
    double var1 = sumsq / Nall - m1 * m1;
    double scaled = (double)g1[0] / sqrt(var1 + 1e-5);
    if (tid == 0) { bn1[0] = (float)m1; bn1[1] = (float)scaled; }
    const double Rinv = 1.0 / (double)ROWSX;
    if (tid < 64) xbarn[tid] = (float)((S1d[tid] * Rinv - m1) * scaled) + be1[0];
#pragma unroll
    for (int e = 0; e < 16; ++e) {
        int idx = tid * 16 + e;
        int a = idx >> 6, b = idx & 63;
        double cov = S2d[idx] * Rinv - (S1d[a] * Rinv) * (S1d[b] * Rinv);
        covn[idx] = (float)(cov * scaled * scaled);
    }
}

// ---------------- K5: analytic BN2 constants per feature -------------------
__global__ __launch_bounds__(64) void k_bn2(
        const float* __restrict__ covn, const float* __restrict__ xbarn,
        const __hip_bfloat16* __restrict__ W2b,
        const float* __restrict__ g2, const float* __restrict__ be2,
        float* __restrict__ alpha, float* __restrict__ beta) {
    int f = blockIdx.x;
    int j = threadIdx.x;
    float wj = __bfloat162float(W2b[(size_t)f * 64 + j]);
    float t1 = 0.f;
    for (int b = 0; b < 64; ++b)
        t1 += covn[j * 64 + b] * __bfloat162float(W2b[(size_t)f * 64 + b]);
    float vc = wj * t1;
    float mc = wj * xbarn[j];
#pragma unroll
    for (int off = 32; off; off >>= 1) {
        vc += __shfl_down(vc, off);
        mc += __shfl_down(mc, off);
    }
    if (j == 0) {
        float t2 = g2[f] * rsqrtf(vc + 1e-5f);
        alpha[f] = t2;
        beta[f] = -t2 * mc + be2[f];
    }
}

// ---------------- K6: MFMA MLP: u = bf16(x_n) @ W2b^T, z = sum relu(a*u+b)*w3
__global__ __launch_bounds__(256, 2) void k_mlp_mfma(
        const float* __restrict__ xbuf, const float* __restrict__ bn1,
        const float* __restrict__ be1, const __hip_bfloat16* __restrict__ W2b,
        const float* __restrict__ alpha, const float* __restrict__ beta,
        const float* __restrict__ W3, const float* __restrict__ b3,
        float* __restrict__ z) {
    constexpr int LDR = 72;
    __shared__ __attribute__((aligned(16))) unsigned short Xs[128 * LDR];
    __shared__ __attribute__((aligned(16))) unsigned short Ws[128 * LDR];
    __shared__ float abw[3 * 128];
    const unsigned short* W2u = reinterpret_cast<const unsigned short*>(W2b);
    int tid = threadIdx.x;
    int w = tid >> 6, l = tid & 63, h = l >> 5, c = l & 31;
    int r0 = blockIdx.x * 128;
    float m1 = bn1[0], sc = bn1[1], sh = be1[0];

#pragma unroll
    for (int i = 0; i < 4; ++i) {
        int id = i * 256 + tid;
        int row = id >> 3, cg = id & 7;
        const float* src = xbuf + (size_t)(r0 + row) * 64 + cg * 8;
        float4 v0 = *reinterpret_cast<const float4*>(src);
        float4 v1 = *reinterpret_cast<const float4*>(src + 4);
        union { __hip_bfloat16 hh[8]; uint4 u; } o;
        o.hh[0] = __float2bfloat16((v0.x - m1) * sc + sh);
        o.hh[1] = __float2bfloat16((v0.y - m1) * sc + sh);
        o.hh[2] = __float2bfloat16((v0.z - m1) * sc + sh);
        o.hh[3] = __float2bfloat16((v0.w - m1) * sc + sh);
        o.hh[4] = __float2bfloat16((v1.x - m1) * sc + sh);
        o.hh[5] = __float2bfloat16((v1.y - m1) * sc + sh);
        o.hh[6] = __float2bfloat16((v1.z - m1) * sc + sh);
        o.hh[7] = __float2bfloat16((v1.w - m1) * sc + sh);
        *reinterpret_cast<uint4*>(&Xs[row * LDR + cg * 8]) = o.u;
    }

    float zacc[16] = {};
    for (int fc = 0; fc < FF / 128; ++fc) {
#pragma unroll
        for (int i = 0; i < 4; ++i) {
            int id = i * 256 + tid;
            int row = id >> 3, cg = id & 7;
            uint4 v = *reinterpret_cast<const uint4*>(W2u + (size_t)(fc * 128 + row) * 64 + cg * 8);
            *reinterpret_cast<uint4*>(&Ws[row * LDR + cg * 8]) = v;
        }
        if (tid < 128) {
            int f = fc * 128 + tid;
            abw[tid] = alpha[f];
            abw[128 + tid] = beta[f];
            abw[256 + tid] = W3[f];
        }
        __syncthreads();
        bf16x8 a[4];
#pragma unroll
        for (int st = 0; st < 4; ++st)
            a[st] = *reinterpret_cast<const bf16x8*>(&Xs[(w * 32 + c) * LDR + st * 16 + h * 8]);
#pragma unroll
        for (int nq = 0; nq < 4; ++nq) {
            floatx16 u = {};
#pragma unroll
            for (int st = 0; st < 4; ++st) {
                bf16x8 b = *reinterpret_cast<const bf16x8*>(&Ws[(nq * 32 + c) * LDR + st * 16 + h * 8]);
                u = __builtin_amdgcn_mfma_f32_32x32x16_bf16(a[st], b, u, 0, 0, 0);
            }
            float al = abw[nq * 32 + c];
            float bt = abw[128 + nq * 32 + c];
            float w3 = abw[256 + nq * 32 + c];
#pragma unroll
            for (int r = 0; r < 16; ++r)
                zacc[r] += fmaxf(al * u[r] + bt, 0.f) * w3;
        }
        __syncthreads();
    }
#pragma unroll
    for (int stage = 1; stage < 32; stage <<= 1)
#pragma unroll
        for (int r = 0; r < 16; ++r)
            zacc[r] += __shfl_xor(zacc[r], stage, 64);
    if (c == 0) {
        float bb = b3[0];
#pragma unroll
        for (int r = 0; r < 16; ++r) {
            int row = r0 + w * 32 + (r & 3) + 8 * (r >> 2) + 4 * h;
            z[row] = zacc[r] + bb;
        }
    }
}

// ---------------- K7: pair-sum + BN3 stats ---------------------------------
__global__ __launch_bounds__(256) void k_pair(const float* __restrict__ z,
        float* __restrict__ v, double* __restrict__ sums3) {
    int i = blockIdx.x * 256 + threadIdx.x;
    float val = z[2 * i] + z[2 * i + 1];
    v[i] = val;
    float s = val, ss = val * val;
#pragma unroll
    for (int off = 32; off; off >>= 1) {
        s += __shfl_down(s, off);
        ss += __shfl_down(ss, off);
    }
    __shared__ float bs[4], bss[4];
    int lane = threadIdx.x & 63, w = threadIdx.x >> 6;
    if (lane == 0) { bs[w] = s; bss[w] = ss; }
    __syncthreads();
    if (threadIdx.x == 0) {
        atomicAdd(&sums3[0], (double)(bs[0] + bs[1] + bs[2] + bs[3]));
        atomicAdd(&sums3[1], (double)(bss[0] + bss[1] + bss[2] + bss[3]));
    }
}

// ---------------- K8: finalize BN3 -----------------------------------------
__global__ void k_fin3(const double* __restrict__ sums3, const float* __restrict__ g3,
                       float* __restrict__ bn3) {
    double m = sums3[0] / (double)PAIRS;
    double var = sums3[1] / (double)PAIRS - m * m;
    bn3[0] = (float)m;
    bn3[1] = (float)((double)g3[0] / sqrt(var + 1e-5));
}

// ---------------- K9: write output -----------------------------------------
__global__ void k_out(const float* __restrict__ v, const float* __restrict__ bn3,
                      const float* __restrict__ be3, float* __restrict__ out) {
    int i = blockIdx.x * 256 + threadIdx.x;
    if (i < PAIRS) out[i] = (v[i] - bn3[0]) * bn3[1] + be3[0];
}

extern "C" void kernel_launch(void* const* d_in, const int* in_sizes, int n_in,
                              void* d_out, int out_size, void* d_ws, size_t ws_size,
                              hipStream_t stream) {
    (void)in_sizes; (void)n_in; (void)out_size; (void)ws_size;
    const float* tgt = (const float*)d_in[0];
    const float* mem = (const float*)d_in[1];
    const float* W1  = (const float*)d_in[2];
    const float* b1  = (const float*)d_in[3];
    const float* se  = (const float*)d_in[4];
    const float* W2  = (const float*)d_in[5];
    const float* b2  = (const float*)d_in[6];
    const float* W3  = (const float*)d_in[7];
    const float* b3  = (const float*)d_in[8];
    const float* g1  = (const float*)d_in[9];
    const float* be1 = (const float*)d_in[10];
    const float* g2  = (const float*)d_in[11];
    const float* be2 = (const float*)d_in[12];
    const float* g3  = (const float*)d_in[13];
    const float* be3 = (const float*)d_in[14];
    const int*  flag = (const int*)d_in[15];
    (void)b2;  // cancels analytically through BN2's mean-subtract
    float* out = (float*)d_out;

    char* ws = (char*)d_ws;
    size_t off = 0;
    auto alloc = [&](size_t bytes) -> void* {
        void* p = ws + off;
        off = (off + bytes + 255) & ~(size_t)255;
        return p;
    };
    float* sig   = (float*)alloc((size_t)SSZ * SSZ * 4);
    __hip_bfloat16* Xb  = (__hip_bfloat16*)alloc((size_t)NX * D * 2);   // 21 MB
    __hip_bfloat16* W1b = (__hip_bfloat16*)alloc((size_t)D * D * 2);    // 0.5 MB
    __hip_bfloat16* W2b = (__hip_bfloat16*)alloc((size_t)FF * 64 * 2);  // 0.25 MB
    __hip_bfloat16* QKf = (__hip_bfloat16*)alloc((size_t)NX * D * 2);   // 21 MB (fragment layout)
    float* xbuf  = (float*)alloc((size_t)ROWSX * 64 * 4);               // 8 MB
    float* z     = (float*)alloc((size_t)ROWSX * 4);
    float* v     = (float*)alloc((size_t)PAIRS * 4);
    float* alpha = (float*)alloc((size_t)FF * 4);
    float* beta  = (float*)alloc((size_t)FF * 4);
    float* xbarn = (float*)alloc(64 * 4);
    float* covn  = (float*)alloc(64 * 64 * 4);
    float* bn1   = (float*)alloc(16);
    float* bn3   = (float*)alloc(16);
    size_t statsStart = off;
    double* S1d   = (double*)alloc(64 * 8);
    double* S2d   = (double*)alloc(64 * 64 * 8);
    double* sums3 = (double*)alloc(2 * 8);
    size_t statsEnd = off;

    hipMemsetAsync(ws + statsStart, 0, statsEnd - statsStart, stream);

    k_sig<<<16, 256, 0, stream>>>(se, flag, sig);
    constexpr int CVT4 = (NX * D + D * D + FF * 64) / 4;
    k_cvt<<<(CVT4 + 255) / 256, 256, 0, stream>>>(tgt, mem, W1, W2, Xb, W1b, W2b);
    k_gemm1_mfma<<<(NX / 128) * (D / 128), 256, 0, stream>>>(Xb, W1b, b1, flag, QKf);
    k_score_mfma<<<NQ * (NK / 4), 256, 0, stream>>>(QKf, sig, xbuf);
    k_stats1<<<128, 256, 0, stream>>>(xbuf, S1d, S2d);
    k_fin1<<<1, 256, 0, stream>>>(S1d, S2d, g1, be1, bn1, xbarn, covn);
    k_bn2<<<FF, 64, 0, stream>>>(covn, xbarn, W2b, g2, be2, alpha, beta);
    k_mlp_mfma<<<ROWSX / 128, 256, 0, stream>>>(xbuf, bn1, be1, W2b, alpha, beta, W3, b3, z);
    k_pair<<<PAIRS / 256, 256, 0, stream>>>(z, v, sums3);
    k_fin3<<<1, 1, 0, stream>>>(sums3, g3, bn3);
    k_out<<<PAIRS / 256, 256, 0, stream>>>(v, bn3, be3, out);
}

// Round 3
// 356.927 us; speedup vs baseline: 1.0984x; 1.0353x over previous
//
#include <hip/hip_runtime.h>
#include <hip/hip_bf16.h>
#include <math.h>
#include <float.h>

// dims
constexpr int NQ = 64, NK = 256, SSZ = 64, D = 512, FF = 2048;
constexpr int PAIRS = NQ * NK;          // 16384
constexpr int ROWSX = 2 * PAIRS;        // 32768
constexpr int NX = (NQ + NK) * SSZ;     // 20480 rows of X = [tgt;mem]

typedef __bf16 bf16x8 __attribute__((ext_vector_type(8)));
typedef float floatx16 __attribute__((ext_vector_type(16)));

// async global->LDS, 16 B per lane; LDS dest = wave-uniform base + lane*16
__device__ __forceinline__ void gl2lds16(const unsigned short* g, unsigned short* l) {
    __builtin_amdgcn_global_load_lds(
        (const __attribute__((address_space(1))) unsigned int*)(g),
        (__attribute__((address_space(3))) unsigned int*)(l),
        16, 0, 0);
}

// Fragment layout for QKf: block (rg, kgrp) = 1 KB at ((rg*32 + kgrp)*1024):
//   lane l (16 B entry at l*16) holds row rg*32 + (l&31),
//   k elems kgrp*16 + (l>>5)*8 .. +7  == exactly the 32x32x16 A/B fragment.

// ---------------- K0: sigmoid of score_embed (or 1.0 if !flag) -------------
__global__ void k_sig(const float* __restrict__ se, const int* __restrict__ flag,
                      float* __restrict__ sig) {
    int i = blockIdx.x * blockDim.x + threadIdx.x;
    if (i < SSZ * SSZ) {
        sig[i] = (*flag) ? 1.0f / (1.0f + expf(-se[i])) : 1.0f;
    }
}

// ---------------- K0b: convert X=[tgt;mem], W1, W2 to bf16 -----------------
__global__ __launch_bounds__(256) void k_cvt(
        const float* __restrict__ tgt, const float* __restrict__ mem,
        const float* __restrict__ W1, const float* __restrict__ W2,
        __hip_bfloat16* __restrict__ Xb, __hip_bfloat16* __restrict__ W1b,
        __hip_bfloat16* __restrict__ W2b) {
    constexpr int T4 = NQ * SSZ * D / 4;   // tgt float4 count
    constexpr int X4 = NX * D / 4;         // X float4 count
    constexpr int W4 = D * D / 4;          // W1 float4 count
    constexpr int V4 = FF * 64 / 4;        // W2 float4 count
    int idx = blockIdx.x * 256 + threadIdx.x;
    if (idx >= X4 + W4 + V4) return;
    const float* src;
    __hip_bfloat16* dst;
    if (idx < T4)           { src = tgt + (size_t)idx * 4;             dst = Xb + (size_t)idx * 4; }
    else if (idx < X4)      { src = mem + (size_t)(idx - T4) * 4;      dst = Xb + (size_t)idx * 4; }
    else if (idx < X4 + W4) { src = W1 + (size_t)(idx - X4) * 4;       dst = W1b + (size_t)(idx - X4) * 4; }
    else                    { src = W2 + (size_t)(idx - X4 - W4) * 4;  dst = W2b + (size_t)(idx - X4 - W4) * 4; }
    float4 v = *reinterpret_cast<const float4*>(src);
    union { __hip_bfloat16 h[4]; uint2 u; } o;
    o.h[0] = __float2bfloat16(v.x); o.h[1] = __float2bfloat16(v.y);
    o.h[2] = __float2bfloat16(v.z); o.h[3] = __float2bfloat16(v.w);
    *reinterpret_cast<uint2*>(dst) = o.u;
}

// ---------------- K1: MFMA GEMM1: QKf = frag(Xb @ W1b^T + b1) --------------
// Swapped-operand MFMA (acc rows = W1 rows n, cols = X rows m) so each thread
// holds 4 consecutive n per reg-quad -> packed 8 B stores directly into the
// fragment layout. Main-loop staging identical to the proven v0 kernel.
__global__ __launch_bounds__(256, 3) void k_gemm1_mfma(
        const __hip_bfloat16* __restrict__ Xb, const __hip_bfloat16* __restrict__ W1b,
        const float* __restrict__ b1, const int* __restrict__ flag,
        __hip_bfloat16* __restrict__ QKf) {
    __shared__ __attribute__((aligned(16))) unsigned short lds[2 * 128 * 64]; // 32 KB
    const unsigned short* Xu = reinterpret_cast<const unsigned short*>(Xb);
    const unsigned short* Wu = reinterpret_cast<const unsigned short*>(W1b);
    unsigned short* Fu = reinterpret_cast<unsigned short*>(QKf);

    int tid = threadIdx.x;
    int bm = blockIdx.x >> 2, bn = blockIdx.x & 3;
    int m0 = bm * 128, n0 = bn * 128;

    if (!(*flag)) {
        // copy X rows into fragment layout (correctness path, flag==0 only)
#pragma unroll
        for (int i = 0; i < 8; ++i) {
            int e = i * 256 + tid;          // 0..2047 entries of 16 B
            int fb = e >> 6;                // frag block 0..31
            int lp = e & 63;                // lane entry
            int rgl = fb >> 3, kgl = fb & 7;
            int row = m0 + rgl * 32 + (lp & 31);
            int col = n0 + kgl * 16 + (lp >> 5) * 8;
            uint4 v = *reinterpret_cast<const uint4*>(Xu + (size_t)row * D + col);
            size_t ofs = ((size_t)((m0 >> 5) + rgl) * 32 + (n0 >> 4) + kgl) * 512 + lp * 8;
            *reinterpret_cast<uint4*>(Fu + ofs) = v;
        }
        return;
    }

    int w = tid >> 6, l = tid & 63, h = l >> 5, c = l & 31;
    int wm = w >> 1, wn = w & 1;
    int chg = (l & 7) ^ (l >> 3);     // swizzled source chunk for this lane
    int cx = c & 7;
    // acc[ni][mi]: n-half ni (W rows), m-half mi (X rows)
    floatx16 acc00 = {}, acc01 = {}, acc10 = {}, acc11 = {};

    for (int kb = 0; kb < D; kb += 64) {
#pragma unroll
        for (int j = 0; j < 8; ++j) {
            int i = w * 8 + j;              // 0..31
            int buf = i >> 4;               // 0: A(X), 1: B(W1)
            int rb = (i & 15) * 8;
            int r = rb + (l >> 3);
            const unsigned short* src = (buf == 0)
                ? (Xu + (size_t)(m0 + r) * D + kb + chg * 8)
                : (Wu + (size_t)(n0 + r) * D + kb + chg * 8);
            gl2lds16(src, lds + buf * 8192 + rb * 64);
        }
        __syncthreads();
        const unsigned short* pA = lds + (wm * 64) * 64;
        const unsigned short* pB = lds + 8192 + (wn * 64) * 64;
#pragma unroll
        for (int st = 0; st < 4; ++st) {
            int ko = ((st * 2 + h) ^ cx) * 8;
            bf16x8 a0 = *reinterpret_cast<const bf16x8*>(pA + c * 64 + ko);
            bf16x8 a1 = *reinterpret_cast<const bf16x8*>(pA + (32 + c) * 64 + ko);
            bf16x8 b0 = *reinterpret_cast<const bf16x8*>(pB + c * 64 + ko);
            bf16x8 b1v = *reinterpret_cast<const bf16x8*>(pB + (32 + c) * 64 + ko);
            acc00 = __builtin_amdgcn_mfma_f32_32x32x16_bf16(b0, a0, acc00, 0, 0, 0);
            acc01 = __builtin_amdgcn_mfma_f32_32x32x16_bf16(b0, a1, acc01, 0, 0, 0);
            acc10 = __builtin_amdgcn_mfma_f32_32x32x16_bf16(b1v, a0, acc10, 0, 0, 0);
            acc11 = __builtin_amdgcn_mfma_f32_32x32x16_bf16(b1v, a1, acc11, 0, 0, 0);
        }
        __syncthreads();
    }

    // epilogue: n = nb + 8g + 4h + q (q=0..3 consecutive -> 8 B pack), m = mb + c
    // frag store: rg = mb>>5, kgrp = (nb>>4) + (g>>1), lane' = c + 32*(g&1), byte 8h
#pragma unroll
    for (int ni = 0; ni < 2; ++ni) {
        int nb = n0 + wn * 64 + ni * 32;
#pragma unroll
        for (int mi = 0; mi < 2; ++mi) {
            const floatx16& A = ni ? (mi ? acc11 : acc10) : (mi ? acc01 : acc00);
            int mb = m0 + wm * 64 + mi * 32;
            size_t rgbase = ((size_t)(mb >> 5) * 32 + (nb >> 4)) * 512;
#pragma unroll
            for (int g = 0; g < 4; ++g) {
                float4 bia = *reinterpret_cast<const float4*>(&b1[nb + 8 * g + 4 * h]);
                union { __hip_bfloat16 hh[4]; uint2 u; } o;
                o.hh[0] = __float2bfloat16(A[4 * g + 0] + bia.x);
                o.hh[1] = __float2bfloat16(A[4 * g + 1] + bia.y);
                o.hh[2] = __float2bfloat16(A[4 * g + 2] + bia.z);
                o.hh[3] = __float2bfloat16(A[4 * g + 3] + bia.w);
                *reinterpret_cast<uint2*>(Fu + rgbase + (size_t)(g >> 1) * 512
                                          + (c + 32 * (g & 1)) * 8 + 4 * h) = o.u;
            }
        }
    }
}

// ---------------- K2: MFMA score einsum + sigmoid + dual max ---------------
// v4: Q tile (contiguous 64 KB in fragment layout, shared by all 4 waves) is
// staged ONCE into LDS; K fragments stay register-direct (zero block reuse).
// One barrier total; K-loop is barrier-free with dbuf'd operands.
__global__ __launch_bounds__(256, 2) void k_score_mfma(
        const __hip_bfloat16* __restrict__ QKf, const float* __restrict__ sig,
        float* __restrict__ xbuf) {
    __shared__ __attribute__((aligned(16))) unsigned short lds[40960]; // 64KB Q + 16KB sig
    const unsigned short* Fu = reinterpret_cast<const unsigned short*>(QKf);
    const unsigned short* sigu = reinterpret_cast<const unsigned short*>(sig);

    int tid = threadIdx.x;
    int w = tid >> 6, l = tid & 63, h = l >> 5, c = l & 31;
    int qi = blockIdx.x >> 6, kg = blockIdx.x & 63;

    // stage Q tile (64 KB contiguous at Fu + qi*32768) into LDS, linear order
    const unsigned short* Qg = Fu + (size_t)qi * 32768;
#pragma unroll
    for (int i = 0; i < 16; ++i) {
        int e = i * 256 + tid;          // 16-B entry index
        gl2lds16(Qg + e * 8, lds + e * 8);
    }
    // stage sig (16 KB) behind Q
#pragma unroll
    for (int j = 0; j < 4; ++j) {
        int e = j * 256 + tid;
        gl2lds16(sigu + e * 8, lds + 32768 + e * 8);
    }

    // K fragment pointers (each load = 1 KB contiguous across the wave)
    const unsigned short* pKA = Fu + ((size_t)(128 + (kg * 4 + w) * 2) * 32) * 512 + l * 8;
    const unsigned short* pKB = pKA + 32 * 512;

    floatx16 acc00 = {}, acc01 = {}, acc10 = {}, acc11 = {};
    bf16x8 ka0[2][4], ka1[2][4], qb0[2][4], qb1[2][4];
#pragma unroll
    for (int st = 0; st < 4; ++st) {
        ka0[0][st] = *reinterpret_cast<const bf16x8*>(pKA + st * 512);
        ka1[0][st] = *reinterpret_cast<const bf16x8*>(pKB + st * 512);
    }
    __syncthreads();   // Q + sig staged (vmcnt drained); K step-0 also complete

    const unsigned short* qlds = lds + l * 8;
#pragma unroll
    for (int st = 0; st < 4; ++st) {
        qb0[0][st] = *reinterpret_cast<const bf16x8*>(qlds + st * 512);
        qb1[0][st] = *reinterpret_cast<const bf16x8*>(qlds + 16384 + st * 512);
    }

#pragma unroll
    for (int kbi = 0; kbi < 8; ++kbi) {
        const int cur = kbi & 1, nxt = cur ^ 1;
        if (kbi < 7) {
            pKA += 4 * 512; pKB += 4 * 512;
#pragma unroll
            for (int st = 0; st < 4; ++st) {
                ka0[nxt][st] = *reinterpret_cast<const bf16x8*>(pKA + st * 512);
                ka1[nxt][st] = *reinterpret_cast<const bf16x8*>(pKB + st * 512);
            }
#pragma unroll
            for (int st = 0; st < 4; ++st) {
                int kgrp = (kbi + 1) * 4 + st;
                qb0[nxt][st] = *reinterpret_cast<const bf16x8*>(qlds + kgrp * 512);
                qb1[nxt][st] = *reinterpret_cast<const bf16x8*>(qlds + 16384 + kgrp * 512);
            }
        }
#pragma unroll
        for (int st = 0; st < 4; ++st) {
            acc00 = __builtin_amdgcn_mfma_f32_32x32x16_bf16(ka0[cur][st], qb0[cur][st], acc00, 0, 0, 0);
            acc01 = __builtin_amdgcn_mfma_f32_32x32x16_bf16(ka0[cur][st], qb1[cur][st], acc01, 0, 0, 0);
            acc10 = __builtin_amdgcn_mfma_f32_32x32x16_bf16(ka1[cur][st], qb0[cur][st], acc10, 0, 0, 0);
            acc11 = __builtin_amdgcn_mfma_f32_32x32x16_bf16(ka1[cur][st], qb1[cur][st], acc11, 0, 0, 0);
        }
    }

    // sig drained at the prologue barrier; no further barrier needed
    float* sigl = reinterpret_cast<float*>(lds + 32768);

    int p = qi * 256 + kg * 4 + w;
    float tmax0 = -FLT_MAX, tmax1 = -FLT_MAX;
    float smax[2][16];
#pragma unroll
    for (int si = 0; si < 2; ++si) {
        const floatx16& A0 = si ? acc10 : acc00;
        const floatx16& A1 = si ? acc11 : acc01;
#pragma unroll
        for (int r = 0; r < 16; ++r) {
            int srow = si * 32 + (r & 3) + 8 * (r >> 2) + 4 * h;
            float v0 = A0[r] * sigl[srow * 64 + c];
            float v1 = A1[r] * sigl[srow * 64 + 32 + c];
            tmax0 = fmaxf(tmax0, v0);
            tmax1 = fmaxf(tmax1, v1);
            smax[si][r] = fmaxf(v0, v1);
        }
    }
    tmax0 = fmaxf(tmax0, __shfl_xor(tmax0, 32, 64));
    tmax1 = fmaxf(tmax1, __shfl_xor(tmax1, 32, 64));
    if (h == 0) {
        xbuf[(size_t)(2 * p) * 64 + c] = tmax0;
        xbuf[(size_t)(2 * p) * 64 + 32 + c] = tmax1;
    }
#pragma unroll
    for (int stage = 1; stage < 32; stage <<= 1) {
#pragma unroll
        for (int si = 0; si < 2; ++si)
#pragma unroll
            for (int r = 0; r < 16; ++r)
                smax[si][r] = fmaxf(smax[si][r], __shfl_xor(smax[si][r], stage, 64));
    }
    if (c == 0) {
#pragma unroll
        for (int si = 0; si < 2; ++si)
#pragma unroll
            for (int r = 0; r < 16; ++r) {
                int srow = si * 32 + (r & 3) + 8 * (r >> 2) + 4 * h;
                xbuf[(size_t)(2 * p + 1) * 64 + srow] = smax[si][r];
            }
    }
}

// ---------------- K3: row stats S1[64], S2[64][64] over xbuf ---------------
__global__ __launch_bounds__(256) void k_stats1(const float* __restrict__ xbuf,
        double* __restrict__ S1d, double* __restrict__ S2d) {
    __shared__ float xr[4][64];
    int tid = threadIdx.x;
    int row0 = blockIdx.x * 256;
    float acc[16] = {};
    float s1 = 0.f;
    int pbase = tid * 16;
    for (int it = 0; it < 64; ++it) {
        int r = row0 + it * 4;
        xr[tid >> 6][tid & 63] = xbuf[(size_t)(r + (tid >> 6)) * 64 + (tid & 63)];
        __syncthreads();
#pragma unroll
        for (int e = 0; e < 16; ++e) {
            int a = (pbase + e) >> 6, b = (pbase + e) & 63;
            acc[e] += xr[0][a] * xr[0][b] + xr[1][a] * xr[1][b]
                    + xr[2][a] * xr[2][b] + xr[3][a] * xr[3][b];
        }
        if (tid < 64) s1 += xr[0][tid] + xr[1][tid] + xr[2][tid] + xr[3][tid];
        __syncthreads();
    }
#pragma unroll
    for (int e = 0; e < 16; ++e) atomicAdd(&S2d[pbase + e], (double)acc[e]);
    if (tid < 64) atomicAdd(&S1d[tid], (double)s1);
}

// ---------------- K4: finalize BN1 + normalized mean/cov -------------------
__global__ __launch_bounds__(256) void k_fin1(
        const double* __restrict__ S1d, const double* __restrict__ S2d,
        const float* __restrict__ g1, const float* __restrict__ be1,
        float* __restrict__ bn1, float* __restrict__ xbarn, float* __restrict__ covn) {
    int tid = threadIdx.x;
    double sum = 0.0, sumsq = 0.0;
    for (int j = 0; j < 64; ++j) { sum += S1d[j]; sumsq += S2d[j * 64 + j]; }
    const double Nall = (double)ROWSX * 64.0;
    double m1 = sum / Nall;
    double var1 = sumsq / Nall - m1 * m1;
    double scaled = (double)g1[0] / sqrt(var1 + 1e-5);
    if (tid == 0) { bn1[0] = (float)m1; bn1[1] = (float)scaled; }
    const double Rinv = 1.0 / (double)ROWSX;
    if (tid < 64) xbarn[tid] = (float)((S1d[tid] * Rinv - m1) * scaled) + be1[0];
#pragma unroll
    for (int e = 0; e < 16; ++e) {
        int idx = tid * 16 + e;
        int a = idx >> 6, b = idx & 63;
        double cov = S2d[idx] * Rinv - (S1d[a] * Rinv) * (S1d[b] * Rinv);
        covn[idx] = (float)(cov * scaled * scaled);
    }
}

// ---------------- K5: analytic BN2 constants per feature -------------------
__global__ __launch_bounds__(64) void k_bn2(
        const float* __restrict__ covn, const float* __restrict__ xbarn,
        const __hip_bfloat16* __restrict__ W2b,
        const float* __restrict__ g2, const float* __restrict__ be2,
        float* __restrict__ alpha, float* __restrict__ beta) {
    int f = blockIdx.x;
    int j = threadIdx.x;
    float wj = __bfloat162float(W2b[(size_t)f * 64 + j]);
    float t1 = 0.f;
    for (int b = 0; b < 64; ++b)
        t1 += covn[j * 64 + b] * __bfloat162float(W2b[(size_t)f * 64 + b]);
    float vc = wj * t1;
    float mc = wj * xbarn[j];
#pragma unroll
    for (int off = 32; off; off >>= 1) {
        vc += __shfl_down(vc, off);
        mc += __shfl_down(mc, off);
    }
    if (j == 0) {
        float t2 = g2[f] * rsqrtf(vc + 1e-5f);
        alpha[f] = t2;
        beta[f] = -t2 * mc + be2[f];
    }
}

// ---------------- K6: MFMA MLP: u = bf16(x_n) @ W2b^T, z = sum relu(a*u+b)*w3
__global__ __launch_bounds__(256, 2) void k_mlp_mfma(
        const float* __restrict__ xbuf, const float* __restrict__ bn1,
        const float* __restrict__ be1, const __hip_bfloat16* __restrict__ W2b,
        const float* __restrict__ alpha, const float* __restrict__ beta,
        const float* __restrict__ W3, const float* __restrict__ b3,
        float* __restrict__ z) {
    constexpr int LDR = 72;
    __shared__ __attribute__((aligned(16))) unsigned short Xs[128 * LDR];
    __shared__ __attribute__((aligned(16))) unsigned short Ws[128 * LDR];
    __shared__ float abw[3 * 128];
    const unsigned short* W2u = reinterpret_cast<const unsigned short*>(W2b);
    int tid = threadIdx.x;
    int w = tid >> 6, l = tid & 63, h = l >> 5, c = l & 31;
    int r0 = blockIdx.x * 128;
    float m1 = bn1[0], sc = bn1[1], sh = be1[0];

#pragma unroll
    for (int i = 0; i < 4; ++i) {
        int id = i * 256 + tid;
        int row = id >> 3, cg = id & 7;
        const float* src = xbuf + (size_t)(r0 + row) * 64 + cg * 8;
        float4 v0 = *reinterpret_cast<const float4*>(src);
        float4 v1 = *reinterpret_cast<const float4*>(src + 4);
        union { __hip_bfloat16 hh[8]; uint4 u; } o;
        o.hh[0] = __float2bfloat16((v0.x - m1) * sc + sh);
        o.hh[1] = __float2bfloat16((v0.y - m1) * sc + sh);
        o.hh[2] = __float2bfloat16((v0.z - m1) * sc + sh);
        o.hh[3] = __float2bfloat16((v0.w - m1) * sc + sh);
        o.hh[4] = __float2bfloat16((v1.x - m1) * sc + sh);
        o.hh[5] = __float2bfloat16((v1.y - m1) * sc + sh);
        o.hh[6] = __float2bfloat16((v1.z - m1) * sc + sh);
        o.hh[7] = __float2bfloat16((v1.w - m1) * sc + sh);
        *reinterpret_cast<uint4*>(&Xs[row * LDR + cg * 8]) = o.u;
    }

    float zacc[16] = {};
    for (int fc = 0; fc < FF / 128; ++fc) {
#pragma unroll
        for (int i = 0; i < 4; ++i) {
            int id = i * 256 + tid;
            int row = id >> 3, cg = id & 7;
            uint4 v = *reinterpret_cast<const uint4*>(W2u + (size_t)(fc * 128 + row) * 64 + cg * 8);
            *reinterpret_cast<uint4*>(&Ws[row * LDR + cg * 8]) = v;
        }
        if (tid < 128) {
            int f = fc * 128 + tid;
            abw[tid] = alpha[f];
            abw[128 + tid] = beta[f];
            abw[256 + tid] = W3[f];
        }
        __syncthreads();
        bf16x8 a[4];
#pragma unroll
        for (int st = 0; st < 4; ++st)
            a[st] = *reinterpret_cast<const bf16x8*>(&Xs[(w * 32 + c) * LDR + st * 16 + h * 8]);
#pragma unroll
        for (int nq = 0; nq < 4; ++nq) {
            floatx16 u = {};
#pragma unroll
            for (int st = 0; st < 4; ++st) {
                bf16x8 b = *reinterpret_cast<const bf16x8*>(&Ws[(nq * 32 + c) * LDR + st * 16 + h * 8]);
                u = __builtin_amdgcn_mfma_f32_32x32x16_bf16(a[st], b, u, 0, 0, 0);
            }
            float al = abw[nq * 32 + c];
            float bt = abw[128 + nq * 32 + c];
            float w3 = abw[256 + nq * 32 + c];
#pragma unroll
            for (int r = 0; r < 16; ++r)
                zacc[r] += fmaxf(al * u[r] + bt, 0.f) * w3;
        }
        __syncthreads();
    }
#pragma unroll
    for (int stage = 1; stage < 32; stage <<= 1)
#pragma unroll
        for (int r = 0; r < 16; ++r)
            zacc[r] += __shfl_xor(zacc[r], stage, 64);
    if (c == 0) {
        float bb = b3[0];
#pragma unroll
        for (int r = 0; r < 16; ++r) {
            int row = r0 + w * 32 + (r & 3) + 8 * (r >> 2) + 4 * h;
            z[row] = zacc[r] + bb;
        }
    }
}

// ---------------- K7: pair-sum + BN3 stats ---------------------------------
__global__ __launch_bounds__(256) void k_pair(const float* __restrict__ z,
        float* __restrict__ v, double* __restrict__ sums3) {
    int i = blockIdx.x * 256 + threadIdx.x;
    float val = z[2 * i] + z[2 * i + 1];
    v[i] = val;
    float s = val, ss = val * val;
#pragma unroll
    for (int off = 32; off; off >>= 1) {
        s += __shfl_down(s, off);
        ss += __shfl_down(ss, off);
    }
    __shared__ float bs[4], bss[4];
    int lane = threadIdx.x & 63, w = threadIdx.x >> 6;
    if (lane == 0) { bs[w] = s; bss[w] = ss; }
    __syncthreads();
    if (threadIdx.x == 0) {
        atomicAdd(&sums3[0], (double)(bs[0] + bs[1] + bs[2] + bs[3]));
        atomicAdd(&sums3[1], (double)(bss[0] + bss[1] + bss[2] + bss[3]));
    }
}

// ---------------- K8: finalize BN3 -----------------------------------------
__global__ void k_fin3(const double* __restrict__ sums3, const float* __restrict__ g3,
                       float* __restrict__ bn3) {
    double m = sums3[0] / (double)PAIRS;
    double var = sums3[1] / (double)PAIRS - m * m;
    bn3[0] = (float)m;
    bn3[1] = (float)((double)g3[0] / sqrt(var + 1e-5));
}

// ---------------- K9: write output -----------------------------------------
__global__ void k_out(const float* __restrict__ v, const float* __restrict__ bn3,
                      const float* __restrict__ be3, float* __restrict__ out) {
    int i = blockIdx.x * 256 + threadIdx.x;
    if (i < PAIRS) out[i] = (v[i] - bn3[0]) * bn3[1] + be3[0];
}

extern "C" void kernel_launch(void* const* d_in, const int* in_sizes, int n_in,
                              void* d_out, int out_size, void* d_ws, size_t ws_size,
                              hipStream_t stream) {
    (void)in_sizes; (void)n_in; (void)out_size; (void)ws_size;
    const float* tgt = (const float*)d_in[0];
    const float* mem = (const float*)d_in[1];
    const float* W1  = (const float*)d_in[2];
    const float* b1  = (const float*)d_in[3];
    const float* se  = (const float*)d_in[4];
    const float* W2  = (const float*)d_in[5];
    const float* b2  = (const float*)d_in[6];
    const float* W3  = (const float*)d_in[7];
    const float* b3  = (const float*)d_in[8];
    const float* g1  = (const float*)d_in[9];
    const float* be1 = (const float*)d_in[10];
    const float* g2  = (const float*)d_in[11];
    const float* be2 = (const float*)d_in[12];
    const float* g3  = (const float*)d_in[13];
    const float* be3 = (const float*)d_in[14];
    const int*  flag = (const int*)d_in[15];
    (void)b2;  // cancels analytically through BN2's mean-subtract
    float* out = (float*)d_out;

    char* ws = (char*)d_ws;
    size_t off = 0;
    auto alloc = [&](size_t bytes) -> void* {
        void* p = ws + off;
        off = (off + bytes + 255) & ~(size_t)255;
        return p;
    };
    float* sig   = (float*)alloc((size_t)SSZ * SSZ * 4);
    __hip_bfloat16* Xb  = (__hip_bfloat16*)alloc((size_t)NX * D * 2);   // 21 MB
    __hip_bfloat16* W1b = (__hip_bfloat16*)alloc((size_t)D * D * 2);    // 0.5 MB
    __hip_bfloat16* W2b = (__hip_bfloat16*)alloc((size_t)FF * 64 * 2);  // 0.25 MB
    __hip_bfloat16* QKf = (__hip_bfloat16*)alloc((size_t)NX * D * 2);   // 21 MB (fragment layout)
    float* xbuf  = (float*)alloc((size_t)ROWSX * 64 * 4);               // 8 MB
    float* z     = (float*)alloc((size_t)ROWSX * 4);
    float* v     = (float*)alloc((size_t)PAIRS * 4);
    float* alpha = (float*)alloc((size_t)FF * 4);
    float* beta  = (float*)alloc((size_t)FF * 4);
    float* xbarn = (float*)alloc(64 * 4);
    float* covn  = (float*)alloc(64 * 64 * 4);
    float* bn1   = (float*)alloc(16);
    float* bn3   = (float*)alloc(16);
    size_t statsStart = off;
    double* S1d   = (double*)alloc(64 * 8);
    double* S2d   = (double*)alloc(64 * 64 * 8);
    double* sums3 = (double*)alloc(2 * 8);
    size_t statsEnd = off;

    hipMemsetAsync(ws + statsStart, 0, statsEnd - statsStart, stream);

    k_sig<<<16, 256, 0, stream>>>(se, flag, sig);
    constexpr int CVT4 = (NX * D + D * D + FF * 64) / 4;
    k_cvt<<<(CVT4 + 255) / 256, 256, 0, stream>>>(tgt, mem, W1, W2, Xb, W1b, W2b);
    k_gemm1_mfma<<<(NX / 128) * (D / 128), 256, 0, stream>>>(Xb, W1b, b1, flag, QKf);
    k_score_mfma<<<NQ * (NK / 4), 256, 0, stream>>>(QKf, sig, xbuf);
    k_stats1<<<128, 256, 0, stream>>>(xbuf, S1d, S2d);
    k_fin1<<<1, 256, 0, stream>>>(S1d, S2d, g1, be1, bn1, xbarn, covn);
    k_bn2<<<FF, 64, 0, stream>>>(covn, xbarn, W2b, g2, be2, alpha, beta);
    k_mlp_mfma<<<ROWSX / 128, 256, 0, stream>>>(xbuf, bn1, be1, W2b, alpha, beta, W3, b3, z);
    k_pair<<<PAIRS / 256, 256, 0, stream>>>(z, v, sums3);
    k_fin3<<<1, 1, 0, stream>>>(sums3, g3, bn3);
    k_out<<<PAIRS / 256, 256, 0, stream>>>(v, bn3, be3, out);
}